// Round 2
// baseline (44867.407 us; speedup 1.0000x reference)
//
#include <hip/hip_runtime.h>
#include <stdint.h>
#include <stddef.h>

#define S_LEN 512
#define BATCH 256
#define NIN   64
#define HD    512
#define G4    2048   // 4*H

typedef _Float16 f16;
typedef _Float16 f16x8 __attribute__((ext_vector_type(8)));
typedef float    f32x4 __attribute__((ext_vector_type(4)));
typedef uint32_t u32x4 __attribute__((ext_vector_type(4)));

// ============================ prep kernels ============================
__global__ void k_f32_to_f16(const float* __restrict__ src, f16* __restrict__ dst, int n) {
  int i = blockIdx.x * 256 + threadIdx.x;
  if (i < n) dst[i] = (f16)src[i];
}

// x [B,S,I] fp32 -> xin [(s*256+b)*64+i] fp16  (seq-major rows for the proj GEMM)
__global__ void k_x_transpose(const float* __restrict__ x, f16* __restrict__ xin) {
  int idx = blockIdx.x * 256 + threadIdx.x;
  int i  = idx & 63;
  int sb = idx >> 6;
  int b  = sb & 255;
  int s  = sb >> 8;
  xin[idx] = (f16)x[((size_t)b * S_LEN + s) * NIN + i];
}

__global__ void k_zero_f16(f16* p, int n) {
  int i = blockIdx.x * 256 + threadIdx.x;
  if (i < n) p[i] = (f16)0.f;
}
__global__ void k_zero_i32(int* p, int n) {
  int i = blockIdx.x * 256 + threadIdx.x;
  if (i < n) p[i] = 0;
}

// ====================== projection GEMM ======================
// C[M,2048] = A[M,K] @ W[2048,K]^T + bias   (A,W,C fp16; accum fp32)
// 128x128 tile, BK=32, 4 waves each 64x64 (4x4 MFMA 16x16x32 tiles).
template<int K>
__global__ __launch_bounds__(256) void k_proj(const f16* __restrict__ A,
                                              const f16* __restrict__ W,
                                              const float* __restrict__ bias,
                                              f16* __restrict__ C) {
  constexpr int PITCH = 40;            // f16/row in LDS: 32 data + 8 pad (kills bank conflicts)
  __shared__ f16 lA[128 * PITCH];
  __shared__ f16 lB[128 * PITCH];
  const int m0 = blockIdx.x * 128;
  const int n0 = blockIdx.y * 128;
  const int tid  = threadIdx.x;
  const int lane = tid & 63;
  const int wave = tid >> 6;
  const int wm = (wave & 1) * 64;
  const int wn = (wave >> 1) * 64;
  const int ln = lane & 15;
  const int quad = lane >> 4;
  const int r  = tid >> 1;             // 0..127 (tile row staged by this thread)
  const int ce = (tid & 1) * 16;       // f16 element offset (0 or 16) = 32B half

  f32x4 acc[4][4] = {};

  for (int kb = 0; kb < K; kb += 32) {
    const f16* ga = A + (size_t)(m0 + r) * K + kb + ce;
    const f16* gb = W + (size_t)(n0 + r) * K + kb + ce;
    u32x4 a0 = *(const u32x4*)ga;
    u32x4 a1 = *(const u32x4*)(ga + 8);
    u32x4 b0 = *(const u32x4*)gb;
    u32x4 b1 = *(const u32x4*)(gb + 8);
    __syncthreads();                   // prior compute done before overwrite
    *(u32x4*)&lA[r * PITCH + ce]     = a0;
    *(u32x4*)&lA[r * PITCH + ce + 8] = a1;
    *(u32x4*)&lB[r * PITCH + ce]     = b0;
    *(u32x4*)&lB[r * PITCH + ce + 8] = b1;
    __syncthreads();
    f16x8 af[4], bf[4];
#pragma unroll
    for (int i = 0; i < 4; i++) {
      af[i] = *(const f16x8*)&lA[(wm + i * 16 + ln) * PITCH + quad * 8];
      bf[i] = *(const f16x8*)&lB[(wn + i * 16 + ln) * PITCH + quad * 8];
    }
#pragma unroll
    for (int mi = 0; mi < 4; mi++)
#pragma unroll
      for (int ni = 0; ni < 4; ni++)
        acc[mi][ni] = __builtin_amdgcn_mfma_f32_16x16x32_f16(af[mi], bf[ni], acc[mi][ni], 0, 0, 0);
  }

  // epilogue: + bias, store fp16.  C/D layout: col=lane&15, row=quad*4+reg (m89/m91 verified)
#pragma unroll
  for (int ni = 0; ni < 4; ni++) {
    const int n = n0 + wn + ni * 16 + ln;
    const float bv = bias[n];
#pragma unroll
    for (int mi = 0; mi < 4; mi++) {
#pragma unroll
      for (int rr = 0; rr < 4; rr++) {
        const int m = m0 + wm + mi * 16 + quad * 4 + rr;
        C[(size_t)m * G4 + n] = (f16)(acc[mi][ni][rr] + bv);
      }
    }
  }
}

// ====================== persistent recurrent kernel (one chunk of T steps) ======================
// Grid: 256 WGs.  blockIdx = gi*16 + bi.
// WG (bi,gi): batch rows [bi*16,+16), hidden cols [gi*32,+32) across all 4 gates.
// W_hh slice lives in VGPRs (wave w = gate w; 2 n-tiles x 16 k-steps of f16x8 frags = 128 VGPRs).
// hbuf has T+1 slots: slot 0 = carry-in h (from previous chunk, or zeros), slot tt+1 = h at step tt.
// At the final step each WG also writes its h slice to slot 0 (carry for the next chunk).
// Synchronization: per-bi counter; WG waits for cnt[bi] >= 16*(t0+tt) before reading slot tt.
__global__ __launch_bounds__(256, 1) void k_recur(
    const f16* __restrict__ Whh,    // [2048, 512] fp16
    const f16* __restrict__ xw,     // [T*256, 2048] fp16 (bias included)
    f16* __restrict__ hbuf,         // [T+1, 256, 512] fp16
    float* __restrict__ cbuf,       // [256, 512] fp32 (carried across chunks)
    int* __restrict__ cnt,          // [16] per-bi counters for this layer (persist across chunks)
    int t0, int T) {
  const int tid  = threadIdx.x;
  const int lane = tid & 63;
  const int wave = tid >> 6;        // = gate index (i,f,g,o)
  const int gi = blockIdx.x >> 4;
  const int bi = blockIdx.x & 15;
  const int ln = lane & 15;
  const int quad = lane >> 4;

  __shared__ f16  lh[16 * 520];     // h-tile [16][512] pitch 520
  __shared__ float lgate[16 * 132]; // gates [16 b][128] fp32, pitch 132

  // --- load W_hh fragments into registers (once) ---
  f16x8 wf[2][16];
#pragma unroll
  for (int nt = 0; nt < 2; nt++) {
#pragma unroll
    for (int ks = 0; ks < 16; ks++) {
      const int grow = wave * HD + gi * 32 + nt * 16 + ln;   // gate row in [2048,512]
      wf[nt][ks] = *(const f16x8*)(Whh + (size_t)grow * HD + ks * 32 + quad * 8);
    }
  }

  // --- c state: 2 elements per thread: b=tid>>5 (+8), hl=tid&31 ---
  const int b_e0 = tid >> 5, hl_e0 = tid & 31;
  const int b_e1 = b_e0 + 8;
  float c0v, c1v;
  if (t0 == 0) {
    c0v = 0.f; c1v = 0.f;
  } else {
    c0v = cbuf[(size_t)(bi * 16 + b_e0) * HD + gi * 32 + hl_e0];
    c1v = cbuf[(size_t)(bi * 16 + b_e1) * HD + gi * 32 + hl_e0];
  }

  int* my = cnt + bi;

  for (int tt = 0; tt < T; tt++) {
    // wait until all 16 producers of this bi-group published step t0+tt-1 (slot tt complete)
    if (tid == 0 && tt > 0) {
      const int need = 16 * (t0 + tt);
      while (__hip_atomic_load(my, __ATOMIC_ACQUIRE, __HIP_MEMORY_SCOPE_AGENT) < need) {
        __builtin_amdgcn_s_sleep(1);
      }
    }
    __syncthreads();

    // stage h slot tt, rows [bi*16,+16), into LDS (coalesced 16B per thread x4)
    const f16* hin = hbuf + (size_t)tt * (BATCH * HD) + (size_t)(bi * 16) * HD;
#pragma unroll
    for (int k = 0; k < 4; k++) {
      const int ch = tid + k * 256;
      const int row = ch >> 6, c8 = ch & 63;
      *(u32x4*)&lh[row * 520 + c8 * 8] = *(const u32x4*)(hin + row * HD + c8 * 8);
    }
    __syncthreads();

    // h @ Whh^T for this WG's 2 n-tiles
    f32x4 acc0 = {0.f, 0.f, 0.f, 0.f}, acc1 = {0.f, 0.f, 0.f, 0.f};
#pragma unroll
    for (int ks = 0; ks < 16; ks++) {
      f16x8 af = *(const f16x8*)&lh[ln * 520 + ks * 32 + quad * 8];
      acc0 = __builtin_amdgcn_mfma_f32_16x16x32_f16(af, wf[0][ks], acc0, 0, 0, 0);
      acc1 = __builtin_amdgcn_mfma_f32_16x16x32_f16(af, wf[1][ks], acc1, 0, 0, 0);
    }
    // scatter C/D frags to gate LDS: row(b)=quad*4+rr, col=wave*32 + nt*16 + ln
#pragma unroll
    for (int rr = 0; rr < 4; rr++) {
      lgate[(quad * 4 + rr) * 132 + wave * 32 + ln]      = acc0[rr];
      lgate[(quad * 4 + rr) * 132 + wave * 32 + 16 + ln] = acc1[rr];
    }
    __syncthreads();

    // elementwise LSTM update (2 (b,hl) pairs per thread)
#pragma unroll
    for (int e = 0; e < 2; e++) {
      const int b  = e ? b_e1 : b_e0;
      const int hl = hl_e0;
      float gi_ = lgate[b * 132 + 0  + hl];
      float gf_ = lgate[b * 132 + 32 + hl];
      float gg_ = lgate[b * 132 + 64 + hl];
      float go_ = lgate[b * 132 + 96 + hl];
      const f16* xwp = xw + (size_t)(tt * 256 + bi * 16 + b) * G4 + gi * 32 + hl;
      gi_ += (float)xwp[0];
      gf_ += (float)xwp[512];
      gg_ += (float)xwp[1024];
      go_ += (float)xwp[1536];
      const float ig = 1.f / (1.f + expf(-gi_));
      const float fg = 1.f / (1.f + expf(-gf_));
      const float gg = gg_ > 0.f ? gg_ : expm1f(gg_);
      const float og = 1.f / (1.f + expf(-go_));
      float cv = e ? c1v : c0v;
      cv = fg * cv + ig * gg;
      if (e) c1v = cv; else c0v = cv;
      const float hv = og * (cv > 0.f ? cv : expm1f(cv));
      f16 hv16 = (f16)hv;
      const size_t col = (size_t)(bi * 16 + b) * HD + gi * 32 + hl;
      hbuf[(size_t)(tt + 1) * (BATCH * HD) + col] = hv16;
      if (tt == T - 1) hbuf[col] = hv16;   // carry-out for next chunk (slot 0)
    }
    __threadfence();        // agent-scope: make h stores visible before publish
    __syncthreads();
    if (tid == 0) __hip_atomic_fetch_add(my, 1, __ATOMIC_RELEASE, __HIP_MEMORY_SCOPE_AGENT);
  }

  // save c state for next chunk
  cbuf[(size_t)(bi * 16 + b_e0) * HD + gi * 32 + hl_e0] = c0v;
  cbuf[(size_t)(bi * 16 + b_e1) * HD + gi * 32 + hl_e0] = c1v;
}

// ====================== final FC: y[b] = h_last[b,:] . fc_w + fc_b ======================
__global__ __launch_bounds__(64) void k_fc(const f16* __restrict__ hlast,
                                           const float* __restrict__ fcw,
                                           const float* __restrict__ fcb,
                                           float* __restrict__ out) {
  const int b = blockIdx.x, lane = threadIdx.x;
  const f16* hp = hlast + (size_t)b * HD + lane * 8;
  float s = 0.f;
#pragma unroll
  for (int j = 0; j < 8; j++) s += (float)hp[j] * fcw[lane * 8 + j];
  for (int off = 32; off; off >>= 1) s += __shfl_down(s, off);
  if (lane == 0) out[b] = s + fcb[0];
}

// ============================ host ============================
extern "C" void kernel_launch(void* const* d_in, const int* in_sizes, int n_in,
                              void* d_out, int out_size, void* d_ws, size_t ws_size,
                              hipStream_t stream) {
  (void)in_sizes; (void)n_in; (void)out_size;
  const float* x      = (const float*)d_in[0];
  const float* wih[3] = {(const float*)d_in[1], (const float*)d_in[4], (const float*)d_in[7]};
  const float* whh[3] = {(const float*)d_in[2], (const float*)d_in[5], (const float*)d_in[8]};
  const float* bia[3] = {(const float*)d_in[3], (const float*)d_in[6], (const float*)d_in[9]};
  const float* fcw = (const float*)d_in[10];
  const float* fcb = (const float*)d_in[11];
  float* out = (float*)d_out;

  char* ws = (char*)d_ws;
  size_t off = 0;
  auto alloc = [&](size_t bytes) -> char* {
    off = (off + 255) & ~(size_t)255;
    char* p = ws + off;
    off += bytes;
    return p;
  };

  // ---- fixed allocations (~28 MB) ----
  f16* xin = (f16*)alloc((size_t)S_LEN * BATCH * NIN * 2);
  f16* wih16[3];
  wih16[0] = (f16*)alloc((size_t)G4 * NIN * 2);
  wih16[1] = (f16*)alloc((size_t)G4 * HD * 2);
  wih16[2] = (f16*)alloc((size_t)G4 * HD * 2);
  f16* whh16[3];
  for (int l = 0; l < 3; l++) whh16[l] = (f16*)alloc((size_t)G4 * HD * 2);
  float* cbuf[3];
  for (int l = 0; l < 3; l++) cbuf[l] = (float*)alloc((size_t)BATCH * HD * 4);
  int* cnt = (int*)alloc(64 * 4);   // 16 counters x 3 layers (padded)

  // ---- adaptive chunk length: largest T in {64,32,16,8,4} that fits ws_size ----
  int T = 64;
  while (T > 4) {
    size_t need = off + 4 * 256 /*align slop*/
                + 3 * ((size_t)(T + 1) * BATCH * HD * 2 + 256)
                + (size_t)T * BATCH * G4 * 2;
    if (need <= ws_size) break;
    T >>= 1;
  }
  f16* hbuf[3];
  for (int l = 0; l < 3; l++) hbuf[l] = (f16*)alloc((size_t)(T + 1) * BATCH * HD * 2);
  f16* xw = (f16*)alloc((size_t)T * BATCH * G4 * 2);

  // ---- prep ----
  {
    int n = S_LEN * BATCH * NIN;
    k_x_transpose<<<dim3(n / 256), dim3(256), 0, stream>>>(x, xin);
  }
  k_f32_to_f16<<<dim3((G4 * NIN + 255) / 256), dim3(256), 0, stream>>>(wih[0], wih16[0], G4 * NIN);
  k_f32_to_f16<<<dim3((G4 * HD + 255) / 256), dim3(256), 0, stream>>>(wih[1], wih16[1], G4 * HD);
  k_f32_to_f16<<<dim3((G4 * HD + 255) / 256), dim3(256), 0, stream>>>(wih[2], wih16[2], G4 * HD);
  for (int l = 0; l < 3; l++)
    k_f32_to_f16<<<dim3((G4 * HD + 255) / 256), dim3(256), 0, stream>>>(whh[l], whh16[l], G4 * HD);
  for (int l = 0; l < 3; l++)
    k_zero_f16<<<dim3((BATCH * HD + 255) / 256), dim3(256), 0, stream>>>(hbuf[l], BATCH * HD);
  k_zero_i32<<<dim3(1), dim3(256), 0, stream>>>(cnt, 64);

  // ---- chunk-interleaved layers ----
  for (int t0 = 0; t0 < S_LEN; t0 += T) {
    for (int l = 0; l < 3; l++) {
      dim3 pg(T * BATCH / 128, G4 / 128);
      if (l == 0) {
        const f16* Achunk = xin + (size_t)t0 * BATCH * NIN;
        k_proj<NIN><<<pg, dim3(256), 0, stream>>>(Achunk, wih16[0], bia[0], xw);
      } else {
        // A = previous layer's h chunk: slots 1..T of hbuf[l-1]
        const f16* Achunk = hbuf[l - 1] + (size_t)BATCH * HD;
        k_proj<HD><<<pg, dim3(256), 0, stream>>>(Achunk, wih16[l], bia[l], xw);
      }
      k_recur<<<dim3(256), dim3(256), 0, stream>>>(whh16[l], xw, hbuf[l], cbuf[l],
                                                   cnt + l * 16, t0, T);
    }
  }

  // ---- final FC: slot 0 of hbuf[2] holds the carry-out = h_{S} of layer 3 ----
  k_fc<<<dim3(BATCH), dim3(64), 0, stream>>>(hbuf[2], fcw, fcb, out);
}

// Round 3
// 8040.582 us; speedup vs baseline: 5.5801x; 5.5801x over previous
//
#include <hip/hip_runtime.h>
#include <stdint.h>
#include <stddef.h>

#define S_LEN 512
#define BATCH 256
#define NIN   64
#define HD    512
#define G4    2048   // 4*H

typedef _Float16 f16;
typedef _Float16 f16x8 __attribute__((ext_vector_type(8)));
typedef float    f32x4 __attribute__((ext_vector_type(4)));
typedef uint32_t u32x4 __attribute__((ext_vector_type(4)));

// ============================ prep kernels ============================
__global__ void k_f32_to_f16(const float* __restrict__ src, f16* __restrict__ dst, int n) {
  int i = blockIdx.x * 256 + threadIdx.x;
  if (i < n) dst[i] = (f16)src[i];
}

// x [B,S,I] fp32 -> xin [(s*256+b)*64+i] fp16  (seq-major rows for the proj GEMM)
__global__ void k_x_transpose(const float* __restrict__ x, f16* __restrict__ xin) {
  int idx = blockIdx.x * 256 + threadIdx.x;
  int i  = idx & 63;
  int sb = idx >> 6;
  int b  = sb & 255;
  int s  = sb >> 8;
  xin[idx] = (f16)x[((size_t)b * S_LEN + s) * NIN + i];
}

__global__ void k_zero_f16(f16* p, int n) {
  int i = blockIdx.x * 256 + threadIdx.x;
  if (i < n) p[i] = (f16)0.f;
}
__global__ void k_zero_i32(int* p, int n) {
  int i = blockIdx.x * 256 + threadIdx.x;
  if (i < n) p[i] = 0;
}

// ====================== projection GEMM ======================
// C[M,2048] = A[M,K] @ W[2048,K]^T + bias   (A,W,C fp16; accum fp32)
// 128x128 tile, BK=32, 4 waves each 64x64 (4x4 MFMA 16x16x32 tiles).
template<int K>
__global__ __launch_bounds__(256) void k_proj(const f16* __restrict__ A,
                                              const f16* __restrict__ W,
                                              const float* __restrict__ bias,
                                              f16* __restrict__ C) {
  constexpr int PITCH = 40;            // f16/row in LDS: 32 data + 8 pad
  __shared__ f16 lA[128 * PITCH];
  __shared__ f16 lB[128 * PITCH];
  const int m0 = blockIdx.x * 128;
  const int n0 = blockIdx.y * 128;
  const int tid  = threadIdx.x;
  const int lane = tid & 63;
  const int wave = tid >> 6;
  const int wm = (wave & 1) * 64;
  const int wn = (wave >> 1) * 64;
  const int ln = lane & 15;
  const int quad = lane >> 4;
  const int r  = tid >> 1;             // 0..127 (tile row staged by this thread)
  const int ce = (tid & 1) * 16;       // f16 element offset (0 or 16) = 32B half

  f32x4 acc[4][4] = {};

  for (int kb = 0; kb < K; kb += 32) {
    const f16* ga = A + (size_t)(m0 + r) * K + kb + ce;
    const f16* gb = W + (size_t)(n0 + r) * K + kb + ce;
    u32x4 a0 = *(const u32x4*)ga;
    u32x4 a1 = *(const u32x4*)(ga + 8);
    u32x4 b0 = *(const u32x4*)gb;
    u32x4 b1 = *(const u32x4*)(gb + 8);
    __syncthreads();                   // prior compute done before overwrite
    *(u32x4*)&lA[r * PITCH + ce]     = a0;
    *(u32x4*)&lA[r * PITCH + ce + 8] = a1;
    *(u32x4*)&lB[r * PITCH + ce]     = b0;
    *(u32x4*)&lB[r * PITCH + ce + 8] = b1;
    __syncthreads();
    f16x8 af[4], bf[4];
#pragma unroll
    for (int i = 0; i < 4; i++) {
      af[i] = *(const f16x8*)&lA[(wm + i * 16 + ln) * PITCH + quad * 8];
      bf[i] = *(const f16x8*)&lB[(wn + i * 16 + ln) * PITCH + quad * 8];
    }
#pragma unroll
    for (int mi = 0; mi < 4; mi++)
#pragma unroll
      for (int ni = 0; ni < 4; ni++)
        acc[mi][ni] = __builtin_amdgcn_mfma_f32_16x16x32_f16(af[mi], bf[ni], acc[mi][ni], 0, 0, 0);
  }

  // epilogue: + bias, store fp16.  (layout verified end-to-end in R2)
#pragma unroll
  for (int ni = 0; ni < 4; ni++) {
    const int n = n0 + wn + ni * 16 + ln;
    const float bv = bias[n];
#pragma unroll
    for (int mi = 0; mi < 4; mi++) {
#pragma unroll
      for (int rr = 0; rr < 4; rr++) {
        const int m = m0 + wm + mi * 16 + quad * 4 + rr;
        C[(size_t)m * G4 + n] = (f16)(acc[mi][ni][rr] + bv);
      }
    }
  }
}

// ====================== persistent recurrent kernel (one chunk of T steps) ======================
// Grid: 256 WGs x 512 threads.  blockIdx = gi*16 + bi  (group {bi, gi=0..15} -> same XCD under %8).
// WG (bi,gi): batch rows [bi*16,+16), hidden cols [gi*32,+32) across all 4 gates (128 gate-cols).
// 8 waves: wave w owns gate g=w>>1, sub-tile (w&1): 16 gate-cols, weights in wf[16] = 64 VGPRs.
// Cross-WG h exchange: relaxed agent-scope atomics ONLY (write-through / L2-bypass) -> no
// buffer_inv/buffer_wbl2 in the hot loop.  Flag: relaxed poll + relaxed fetch_add; ordering
// via __syncthreads vmcnt drain + issue order.
__global__ __launch_bounds__(512, 2) void k_recur(
    const f16* __restrict__ Whh,    // [2048, 512] fp16
    const f16* __restrict__ xw,     // [T*256, 2048] fp16 (bias included)
    f16* __restrict__ hbuf,         // [T+1, 256, 512] fp16; slot 0 = carry-in, slot tt+1 = h at tt
    float* __restrict__ cbuf,       // [256, 512] fp32 (carried across chunks)
    int* __restrict__ cnt,          // [16] per-bi counters for this layer (persist across chunks)
    int t0, int T) {
  const int tid  = threadIdx.x;
  const int lane = tid & 63;
  const int wave = tid >> 6;        // 0..7
  const int gi = blockIdx.x >> 4;
  const int bi = blockIdx.x & 15;
  const int ln = lane & 15;
  const int quad = lane >> 4;

  __shared__ f16  lh[16 * 520];     // h-tile [16][512] pitch 520
  __shared__ float lgate[16 * 132]; // gates [16 b][128] fp32, pitch 132

  // --- load W_hh fragments into registers (once): wave w -> gate w>>1, subtile w&1 ---
  const int grow = (wave >> 1) * HD + gi * 32 + (wave & 1) * 16 + ln;  // row in [2048,512]
  f16x8 wf[16];
#pragma unroll
  for (int ks = 0; ks < 16; ks++)
    wf[ks] = *(const f16x8*)(Whh + (size_t)grow * HD + ks * 32 + quad * 8);

  // --- per-thread state: one (b,hl) element: b=tid>>5 (0..15), hl=tid&31 ---
  const int b_  = tid >> 5;
  const int hl_ = tid & 31;
  float cv;
  if (t0 == 0) cv = 0.f;
  else         cv = cbuf[(size_t)(bi * 16 + b_) * HD + gi * 32 + hl_];

  int* my = cnt + bi;
  unsigned short* hb16 = (unsigned short*)hbuf;

  for (int tt = 0; tt < T; tt++) {
    // wait until all 16 producers of this bi-group published step t0+tt-1 (slot tt complete)
    if (tid == 0 && tt > 0) {
      const int need = 16 * (t0 + tt);
      while (__hip_atomic_load(my, __ATOMIC_RELAXED, __HIP_MEMORY_SCOPE_AGENT) < need) {
        __builtin_amdgcn_s_sleep(1);
      }
    }
    __syncthreads();

    // stage h slot tt, rows [bi*16,+16), into LDS via relaxed agent dword loads (L2-bypass)
    {
      unsigned int* hin32 = (unsigned int*)(hbuf + (size_t)tt * (BATCH * HD) + (size_t)(bi * 16) * HD);
#pragma unroll
      for (int i = 0; i < 8; i++) {
        const int c = i * 512 + tid;            // 0..4095 dwords (16 rows x 256)
        const int row = c >> 8, dw = c & 255;
        unsigned int v = __hip_atomic_load(hin32 + c, __ATOMIC_RELAXED, __HIP_MEMORY_SCOPE_AGENT);
        *(unsigned int*)&lh[row * 520 + dw * 2] = v;
      }
    }

    // prefetch this thread's xw gate values (independent of LDS) before the barrier
    const f16* xwp = xw + (size_t)(tt * 256 + bi * 16 + b_) * G4 + gi * 32 + hl_;
    float xg0 = (float)xwp[0];
    float xg1 = (float)xwp[512];
    float xg2 = (float)xwp[1024];
    float xg3 = (float)xwp[1536];
    __syncthreads();

    // h @ Whh^T : each wave 16 gate-cols, one 16x16x(512) accumulation
    f32x4 acc = {0.f, 0.f, 0.f, 0.f};
#pragma unroll
    for (int ks = 0; ks < 16; ks++) {
      f16x8 af = *(const f16x8*)&lh[ln * 520 + ks * 32 + quad * 8];
      acc = __builtin_amdgcn_mfma_f32_16x16x32_f16(af, wf[ks], acc, 0, 0, 0);
    }
    // scatter C/D frags: b-row = quad*4+rr, gate-col = (wave>>1)*32 + (wave&1)*16 + ln
    const int gcol = (wave >> 1) * 32 + (wave & 1) * 16 + ln;
#pragma unroll
    for (int rr = 0; rr < 4; rr++)
      lgate[(quad * 4 + rr) * 132 + gcol] = acc[rr];
    __syncthreads();

    // elementwise LSTM update: one (b,hl) per thread
    {
      float gi_ = lgate[b_ * 132 + 0  + hl_] + xg0;
      float gf_ = lgate[b_ * 132 + 32 + hl_] + xg1;
      float gg_ = lgate[b_ * 132 + 64 + hl_] + xg2;
      float go_ = lgate[b_ * 132 + 96 + hl_] + xg3;
      const float ig = 1.f / (1.f + expf(-gi_));
      const float fg = 1.f / (1.f + expf(-gf_));
      const float gg = gg_ > 0.f ? gg_ : expm1f(gg_);
      const float og = 1.f / (1.f + expf(-go_));
      cv = fg * cv + ig * gg;
      const float hv = og * (cv > 0.f ? cv : expm1f(cv));
      f16 hv16 = (f16)hv;
      unsigned short us;
      __builtin_memcpy(&us, &hv16, 2);
      const size_t col = (size_t)(bi * 16 + b_) * HD + gi * 32 + hl_;
      __hip_atomic_store(hb16 + (size_t)(tt + 1) * (BATCH * HD) + col, us,
                         __ATOMIC_RELAXED, __HIP_MEMORY_SCOPE_AGENT);
      if (tt == T - 1)
        __hip_atomic_store(hb16 + col, us, __ATOMIC_RELAXED, __HIP_MEMORY_SCOPE_AGENT);
    }
    __syncthreads();   // drains each wave's vmcnt -> all h stores at coherence point
    if (tid == 0)
      __hip_atomic_fetch_add(my, 1, __ATOMIC_RELAXED, __HIP_MEMORY_SCOPE_AGENT);
  }

  // save c state for next chunk
  cbuf[(size_t)(bi * 16 + b_) * HD + gi * 32 + hl_] = cv;
}

// ====================== final FC: y[b] = h_last[b,:] . fc_w + fc_b ======================
__global__ __launch_bounds__(64) void k_fc(const f16* __restrict__ hlast,
                                           const float* __restrict__ fcw,
                                           const float* __restrict__ fcb,
                                           float* __restrict__ out) {
  const int b = blockIdx.x, lane = threadIdx.x;
  const f16* hp = hlast + (size_t)b * HD + lane * 8;
  float s = 0.f;
#pragma unroll
  for (int j = 0; j < 8; j++) s += (float)hp[j] * fcw[lane * 8 + j];
  for (int off = 32; off; off >>= 1) s += __shfl_down(s, off);
  if (lane == 0) out[b] = s + fcb[0];
}

// ============================ host ============================
extern "C" void kernel_launch(void* const* d_in, const int* in_sizes, int n_in,
                              void* d_out, int out_size, void* d_ws, size_t ws_size,
                              hipStream_t stream) {
  (void)in_sizes; (void)n_in; (void)out_size;
  const float* x      = (const float*)d_in[0];
  const float* wih[3] = {(const float*)d_in[1], (const float*)d_in[4], (const float*)d_in[7]};
  const float* whh[3] = {(const float*)d_in[2], (const float*)d_in[5], (const float*)d_in[8]};
  const float* bia[3] = {(const float*)d_in[3], (const float*)d_in[6], (const float*)d_in[9]};
  const float* fcw = (const float*)d_in[10];
  const float* fcb = (const float*)d_in[11];
  float* out = (float*)d_out;

  char* ws = (char*)d_ws;
  size_t off = 0;
  auto alloc = [&](size_t bytes) -> char* {
    off = (off + 255) & ~(size_t)255;
    char* p = ws + off;
    off += bytes;
    return p;
  };

  // ---- fixed allocations (~28 MB) ----
  f16* xin = (f16*)alloc((size_t)S_LEN * BATCH * NIN * 2);
  f16* wih16[3];
  wih16[0] = (f16*)alloc((size_t)G4 * NIN * 2);
  wih16[1] = (f16*)alloc((size_t)G4 * HD * 2);
  wih16[2] = (f16*)alloc((size_t)G4 * HD * 2);
  f16* whh16[3];
  for (int l = 0; l < 3; l++) whh16[l] = (f16*)alloc((size_t)G4 * HD * 2);
  float* cbuf[3];
  for (int l = 0; l < 3; l++) cbuf[l] = (float*)alloc((size_t)BATCH * HD * 4);
  int* cnt = (int*)alloc(64 * 4);   // 16 counters x 3 layers (padded)

  // ---- adaptive chunk length: largest T in {64,32,16,8,4} that fits ws_size ----
  int T = 64;
  while (T > 4) {
    size_t need = off + 4 * 256 /*align slop*/
                + 3 * ((size_t)(T + 1) * BATCH * HD * 2 + 256)
                + (size_t)T * BATCH * G4 * 2;
    if (need <= ws_size) break;
    T >>= 1;
  }
  f16* hbuf[3];
  for (int l = 0; l < 3; l++) hbuf[l] = (f16*)alloc((size_t)(T + 1) * BATCH * HD * 2);
  f16* xw = (f16*)alloc((size_t)T * BATCH * G4 * 2);

  // ---- prep ----
  {
    int n = S_LEN * BATCH * NIN;
    k_x_transpose<<<dim3(n / 256), dim3(256), 0, stream>>>(x, xin);
  }
  k_f32_to_f16<<<dim3((G4 * NIN + 255) / 256), dim3(256), 0, stream>>>(wih[0], wih16[0], G4 * NIN);
  k_f32_to_f16<<<dim3((G4 * HD + 255) / 256), dim3(256), 0, stream>>>(wih[1], wih16[1], G4 * HD);
  k_f32_to_f16<<<dim3((G4 * HD + 255) / 256), dim3(256), 0, stream>>>(wih[2], wih16[2], G4 * HD);
  for (int l = 0; l < 3; l++)
    k_f32_to_f16<<<dim3((G4 * HD + 255) / 256), dim3(256), 0, stream>>>(whh[l], whh16[l], G4 * HD);
  for (int l = 0; l < 3; l++)
    k_zero_f16<<<dim3((BATCH * HD + 255) / 256), dim3(256), 0, stream>>>(hbuf[l], BATCH * HD);
  k_zero_i32<<<dim3(1), dim3(256), 0, stream>>>(cnt, 64);

  // ---- chunk-interleaved layers ----
  for (int t0 = 0; t0 < S_LEN; t0 += T) {
    for (int l = 0; l < 3; l++) {
      dim3 pg(T * BATCH / 128, G4 / 128);
      if (l == 0) {
        const f16* Achunk = xin + (size_t)t0 * BATCH * NIN;
        k_proj<NIN><<<pg, dim3(256), 0, stream>>>(Achunk, wih16[0], bia[0], xw);
      } else {
        // A = previous layer's h chunk: slots 1..T of hbuf[l-1]
        const f16* Achunk = hbuf[l - 1] + (size_t)BATCH * HD;
        k_proj<HD><<<pg, dim3(256), 0, stream>>>(Achunk, wih16[l], bia[l], xw);
      }
      k_recur<<<dim3(256), dim3(512), 0, stream>>>(whh16[l], xw, hbuf[l], cbuf[l],
                                                   cnt + l * 16, t0, T);
    }
  }

  // ---- final FC: slot 0 of hbuf[2] holds the carry-out = h_{S} of layer 3 ----
  k_fc<<<dim3(BATCH), dim3(64), 0, stream>>>(hbuf[2], fcw, fcb, out);
}